// Round 14
// baseline (113.332 us; speedup 1.0000x reference)
//
#include <hip/hip_runtime.h>

#define BIG2 1e20f  // fp32(1e10)^2 — matches reference clamp-then-square
#define H 256
#define W 256
#define NPIX (H * W)
typedef unsigned long long u64;
// images: 0..7 = pred batch, 8..15 = target batch
// ws layout:
//   [0, 16384)         double partial[2048]   (one per fused block)
//   [16384, 16448)     int flags[16]          (fg.any() per image)
//   [16448, 16452)     int done_counter       (last-block finalize)
//   [32768, 163840)    u64 rm2[16][4][256]    row-major words: rm2[img][w][r],
//                      bit c = pixel(r, 64w+c) > 0.5
//   [163840, 294912)   u64 colmask[16][256][4] column bits: word q of col j =
//                      rows 64q..64q+63 (bit r = row 64q+r)

// ---------------------------------------------------------------------------
// Kernel A: build row bitmasks, word-major (validated round 11).
// ---------------------------------------------------------------------------
__global__ __launch_bounds__(64) void mask_build(
    const float* __restrict__ pred, const float* __restrict__ targ,
    u64* __restrict__ rm2, int* __restrict__ flags) {
  const int img = blockIdx.x >> 4;  // 0..15
  const int rg = blockIdx.x & 15;   // 16 rows each
  const int lane = threadIdx.x;
  const float* __restrict__ src =
      (img < 8) ? pred + img * NPIX : targ + (img - 8) * NPIX;
  u64* __restrict__ rm = rm2 + img * 1024;

  u64 anyw = 0;
#pragma unroll
  for (int rr = 0; rr < 16; ++rr) {
    const int r = (rg << 4) + rr;
    const u64 w0 = __ballot(src[r * W + lane] > 0.5f);
    const u64 w1 = __ballot(src[r * W + 64 + lane] > 0.5f);
    const u64 w2 = __ballot(src[r * W + 128 + lane] > 0.5f);
    const u64 w3 = __ballot(src[r * W + 192 + lane] > 0.5f);
    anyw |= (w0 | w1 | w2 | w3);
    if (lane == 0) {
      rm[r] = w0; rm[256 + r] = w1; rm[512 + r] = w2; rm[768 + r] = w3;
    }
  }
  if (lane == 0 && anyw) atomicOr(&flags[img], 1);
}

// ---------------------------------------------------------------------------
// 64x64 bit-matrix transpose across a wave (validated round 11, absmax=0).
// ---------------------------------------------------------------------------
__device__ __forceinline__ u64 xpose64(u64 x, const int lane) {
#define XSTEP(S, M)                                                   \
  {                                                                   \
    const u64 y = __shfl_xor(x, S, 64);                               \
    x = (lane & S) ? ((x & (M)) | ((y >> S) & ~(M)))                  \
                   : ((x & ~(M)) | ((y << S) & (M)));                 \
  }
  XSTEP(32, 0xFFFFFFFF00000000ull)
  XSTEP(16, 0xFFFF0000FFFF0000ull)
  XSTEP(8, 0xFF00FF00FF00FF00ull)
  XSTEP(4, 0xF0F0F0F0F0F0F0F0ull)
  XSTEP(2, 0xCCCCCCCCCCCCCCCCull)
  XSTEP(1, 0xAAAAAAAAAAAAAAAAull)
#undef XSTEP
  return x;
}

// ---------------------------------------------------------------------------
// Kernel B: transpose each image's masks ONCE (round-11 post-mortem: the
// fused kernel redid these per ROW — 256x redundant, 48 shfl chains each).
// 64 blocks (16 img x 4 word-cols) x 64 thr. Coalesced u64 loads; 4
// transposes; lane c stores column (64w+c)'s 4 words (8B x 4, stride 32B).
// ---------------------------------------------------------------------------
__global__ __launch_bounds__(64) void xpose_cols(
    const u64* __restrict__ rm2, u64* __restrict__ colmask) {
  const int img = blockIdx.x >> 2;  // 0..15
  const int w = blockIdx.x & 3;     // word column
  const int lane = threadIdx.x;
  const u64* __restrict__ rw = rm2 + img * 1024 + w * 256;
  u64* __restrict__ cm = colmask + img * 1024 + (w * 64 + lane) * 4;
#pragma unroll
  for (int q = 0; q < 4; ++q) {
    cm[q] = xpose64(rw[q * 64 + lane], lane);
  }
}

// ---------------------------------------------------------------------------
// Kernel C: fused vertical-EDT (bit math on preloaded column words) +
// pruned row-EDT + loss + last-block finalize. One block per (batch, row).
// Per thread: 4 x 16B L2 loads of colmask, ~120 branch-free VDIST insts,
// envelope LDS write, pruned scan, reduce. All math paths byte-identical
// to rounds 10/11 (absmax=0 validated).
// ---------------------------------------------------------------------------
__global__ __launch_bounds__(256) void fused_edt_loss(
    const float* __restrict__ pred, const float* __restrict__ targ,
    const u64* __restrict__ colmask, const int* __restrict__ flags,
    double* __restrict__ partial, int* __restrict__ done,
    float* __restrict__ out) {
  const int b = blockIdx.x >> 8;       // batch 0..7
  const int i = blockIdx.x & (H - 1);  // row (block-uniform)
  const int j = threadIdx.x;           // column

  __shared__ __align__(16) float gPF[W], gPB[W], gTF[W], gTB[W];
  __shared__ double wsum[4];
  __shared__ int amLast;

  // ---- load this column's bits for both images (L2-resident, 64B) ----
  const ulonglong2* __restrict__ cp =
      (const ulonglong2*)(colmask + b * 1024 + j * 4);
  const ulonglong2* __restrict__ ct =
      (const ulonglong2*)(colmask + (8 + b) * 1024 + j * 4);
  const ulonglong2 p01 = cp[0], p23 = cp[1];
  const ulonglong2 t01 = ct[0], t23 = ct[1];
  const u64 p0 = p01.x, p1 = p01.y, p2 = p23.x, p3 = p23.y;
  const u64 t0 = t01.x, t1 = t01.y, t2 = t23.x, t3 = t23.y;
  const int pix = b * NPIX + i * W + j;
  const float p = pred[pix];
  const float t = targ[pix];

  // ---- uniform row-split masks (i block-uniform -> SGPR math) ----
  const int gi = i >> 6;
  const int bb = i & 63;
  const u64 lm = (~0ull) >> (63 - bb);  // bits 0..bb
  const u64 hm = (~0ull) << bb;         // bits bb..63
  const u64 k0 = gi == 0 ? lm : ~0ull;
  const u64 k1 = gi < 1 ? 0ull : (gi == 1 ? lm : ~0ull);
  const u64 k2 = gi < 2 ? 0ull : (gi == 2 ? lm : ~0ull);
  const u64 k3 = gi < 3 ? 0ull : lm;
  const u64 q0 = gi > 0 ? 0ull : hm;
  const u64 q1 = gi > 1 ? 0ull : (gi == 1 ? hm : ~0ull);
  const u64 q2 = gi > 2 ? 0ull : (gi == 2 ? hm : ~0ull);
  const u64 q3 = gi == 3 ? hm : ~0ull;

  // ---- vertical nearest-opposite distance, branch-free (validated) ----
#define VDIST(c0, c1, c2, c3, CL, DV2)                                \
  {                                                                   \
    const u64 cw = gi == 0 ? c0 : gi == 1 ? c1 : gi == 2 ? c2 : c3;   \
    CL = (int)((cw >> bb) & 1ull);                                    \
    const u64 inv = CL ? ~0ull : 0ull;                                \
    const u64 o0 = c0 ^ inv, o1 = c1 ^ inv, o2 = c2 ^ inv,            \
              o3 = c3 ^ inv;                                          \
    const u64 u0 = o0 & k0, u1 = o1 & k1, u2 = o2 & k2, u3 = o3 & k3; \
    int last = -30000;                                                \
    if (u0) last = 63 - __builtin_clzll(u0);                          \
    if (u1) last = 127 - __builtin_clzll(u1);                         \
    if (u2) last = 191 - __builtin_clzll(u2);                         \
    if (u3) last = 255 - __builtin_clzll(u3);                         \
    const u64 d0 = o0 & q0, d1 = o1 & q1, d2 = o2 & q2, d3 = o3 & q3; \
    int nxt = 30000;                                                  \
    if (d3) nxt = 192 + __builtin_ctzll(d3);                          \
    if (d2) nxt = 128 + __builtin_ctzll(d2);                          \
    if (d1) nxt = 64 + __builtin_ctzll(d1);                           \
    if (d0) nxt = __builtin_ctzll(d0);                                \
    const int up = i - last, dn = nxt - i;                            \
    const int dv = up < dn ? up : dn;                                 \
    DV2 = (dv >= 1000) ? BIG2 : (float)(dv * dv);                     \
  }
  int clP, clT;
  float dv2P, dv2T;
  VDIST(p0, p1, p2, p3, clP, dv2P)
  VDIST(t0, t1, t2, t3, clT, dv2T)
#undef VDIST

  // envelopes: g_fg[k] = (k fg) ? dv2 : 0 ; g_bg[k] = (k fg) ? 0 : dv2
  gPF[j] = clP ? dv2P : 0.0f;
  gPB[j] = clP ? 0.0f : dv2P;
  gTF[j] = clT ? dv2T : 0.0f;
  gTB[j] = clT ? 0.0f : dv2T;
  __syncthreads();

  // ---- pruned row scan (disjoint support: query own-class envelope) ----
  const float* __restrict__ baseP = clP ? gPF : gPB;
  const float* __restrict__ baseT = clT ? gTF : gTB;
  float bestP = dv2P, bestT = dv2T;  // k=j candidate
  for (int d = 1; d < W; ++d) {
    const float dd = (float)(d * d);
    if (__all((dd >= bestP) & (dd >= bestT))) break;
    const int kL = j - d, kR = j + d;
    const int kLc = kL < 0 ? 0 : kL;
    const int kRc = kR > W - 1 ? W - 1 : kR;
    const float cP = fminf(kL >= 0 ? baseP[kLc] : BIG2,
                           kR < W ? baseP[kRc] : BIG2);
    const float cT = fminf(kL >= 0 ? baseT[kLc] : BIG2,
                           kR < W ? baseT[kRc] : BIG2);
    bestP = fminf(bestP, cP + dd);
    bestT = fminf(bestT, cT + dd);
  }

  // ---- loss + block reduce ----
  const float fP = flags[b] ? 1.0f : 0.0f;  // zero field if no fg (ref)
  const float fT = flags[8 + b] ? 1.0f : 0.0f;
  const float pe = (p - t) * (p - t);
  double c = (double)(pe * (bestP * fP + bestT * fT));
  for (int off = 32; off > 0; off >>= 1) c += __shfl_down(c, off);
  if ((j & 63) == 0) wsum[j >> 6] = c;
  __syncthreads();
  if (j == 0) {
    partial[blockIdx.x] = wsum[0] + wsum[1] + wsum[2] + wsum[3];
    __threadfence();  // release partial before signaling
    amLast = (atomicAdd(done, 1) == (int)gridDim.x - 1);
  }
  __syncthreads();

  // ---- last block: reduce 2048 partials (finalize's exact order) ----
  if (amLast) {
    __threadfence();  // acquire all partials
    double s = 0.0;
#pragma unroll
    for (int k = 0; k < 8; ++k) s += partial[j + (k << 8)];
    for (int off = 32; off > 0; off >>= 1) s += __shfl_down(s, off);
    if ((j & 63) == 0) wsum[j >> 6] = s;
    __syncthreads();
    if (j == 0)
      out[0] = (float)((wsum[0] + wsum[1] + wsum[2] + wsum[3]) *
                       (1.0 / (8.0 * (double)NPIX)));
  }
}

extern "C" void kernel_launch(void* const* d_in, const int* in_sizes, int n_in,
                              void* d_out, int out_size, void* d_ws,
                              size_t ws_size, hipStream_t stream) {
  const float* pred = (const float*)d_in[0];
  const float* targ = (const float*)d_in[1];
  double* partial = (double*)d_ws;
  int* flags = (int*)((char*)d_ws + 16384);
  int* done = (int*)((char*)d_ws + 16448);
  u64* rm2 = (u64*)((char*)d_ws + 32768);
  u64* colmask = (u64*)((char*)d_ws + 163840);

  hipMemsetAsync(flags, 0, 128, stream);  // zero flags[16] + done counter
  mask_build<<<256, 64, 0, stream>>>(pred, targ, rm2, flags);
  xpose_cols<<<64, 64, 0, stream>>>(rm2, colmask);
  fused_edt_loss<<<8 * H, 256, 0, stream>>>(pred, targ, colmask, flags,
                                            partial, done, (float*)d_out);
}

// Round 16
// 77.349 us; speedup vs baseline: 1.4652x; 1.4652x over previous
//
#include <hip/hip_runtime.h>

#define BIG2 1e20f  // fp32(1e10)^2 — matches reference clamp-then-square
#define H 256
#define W 256
#define NPIX (H * W)
typedef unsigned long long u64;
// images: 0..7 = pred batch, 8..15 = target batch
// ws layout:
//   [0, 16384)         double partial[2048]   (one per fused block)
//   [16384, 16448)     int flags[16]          (fg.any() per image)
//   [32768, 163840)    u64 rm2[16][4][256]    row-major words: rm2[img][w][r],
//                      bit c = pixel(r, 64w+c) > 0.5
//   [163840, 294912)   u64 colmask[16][256][4] column bits: word q of col j =
//                      rows 64q..64q+63 (bit r = row 64q+r)
//
// ROUND-14 POST-MORTEM: the amLast inline finalize (2048 blocks x
// {__threadfence + atomicAdd on ONE address}) cost a fixed ~41 us — the
// same-address atomics serialize ~20 ns apiece and all blocks arrive at
// once. Evidence: removing 2/3 of VALU work (VALUBusy 21.7->7.1%) moved
// duration only 48.2->46.5 us. This round: separate 1-block finalize
// (round-10-validated pattern), everything else byte-identical.

// ---------------------------------------------------------------------------
// Kernel A: build row bitmasks, word-major (validated round 11).
// ---------------------------------------------------------------------------
__global__ __launch_bounds__(64) void mask_build(
    const float* __restrict__ pred, const float* __restrict__ targ,
    u64* __restrict__ rm2, int* __restrict__ flags) {
  const int img = blockIdx.x >> 4;  // 0..15
  const int rg = blockIdx.x & 15;   // 16 rows each
  const int lane = threadIdx.x;
  const float* __restrict__ src =
      (img < 8) ? pred + img * NPIX : targ + (img - 8) * NPIX;
  u64* __restrict__ rm = rm2 + img * 1024;

  u64 anyw = 0;
#pragma unroll
  for (int rr = 0; rr < 16; ++rr) {
    const int r = (rg << 4) + rr;
    const u64 w0 = __ballot(src[r * W + lane] > 0.5f);
    const u64 w1 = __ballot(src[r * W + 64 + lane] > 0.5f);
    const u64 w2 = __ballot(src[r * W + 128 + lane] > 0.5f);
    const u64 w3 = __ballot(src[r * W + 192 + lane] > 0.5f);
    anyw |= (w0 | w1 | w2 | w3);
    if (lane == 0) {
      rm[r] = w0; rm[256 + r] = w1; rm[512 + r] = w2; rm[768 + r] = w3;
    }
  }
  if (lane == 0 && anyw) atomicOr(&flags[img], 1);
}

// ---------------------------------------------------------------------------
// 64x64 bit-matrix transpose across a wave (validated round 11, absmax=0).
// ---------------------------------------------------------------------------
__device__ __forceinline__ u64 xpose64(u64 x, const int lane) {
#define XSTEP(S, M)                                                   \
  {                                                                   \
    const u64 y = __shfl_xor(x, S, 64);                               \
    x = (lane & S) ? ((x & (M)) | ((y >> S) & ~(M)))                  \
                   : ((x & ~(M)) | ((y << S) & (M)));                 \
  }
  XSTEP(32, 0xFFFFFFFF00000000ull)
  XSTEP(16, 0xFFFF0000FFFF0000ull)
  XSTEP(8, 0xFF00FF00FF00FF00ull)
  XSTEP(4, 0xF0F0F0F0F0F0F0F0ull)
  XSTEP(2, 0xCCCCCCCCCCCCCCCCull)
  XSTEP(1, 0xAAAAAAAAAAAAAAAAull)
#undef XSTEP
  return x;
}

// ---------------------------------------------------------------------------
// Kernel B: transpose each image's masks ONCE (validated round 14:
// VALUBusy 21.7->7.1% confirmed the hoist removed the redundant work).
// ---------------------------------------------------------------------------
__global__ __launch_bounds__(64) void xpose_cols(
    const u64* __restrict__ rm2, u64* __restrict__ colmask) {
  const int img = blockIdx.x >> 2;  // 0..15
  const int w = blockIdx.x & 3;     // word column
  const int lane = threadIdx.x;
  const u64* __restrict__ rw = rm2 + img * 1024 + w * 256;
  u64* __restrict__ cm = colmask + img * 1024 + (w * 64 + lane) * 4;
#pragma unroll
  for (int q = 0; q < 4; ++q) {
    cm[q] = xpose64(rw[q * 64 + lane], lane);
  }
}

// ---------------------------------------------------------------------------
// Kernel C: fused vertical-EDT (bit math on preloaded column words) +
// pruned row-EDT + loss. One block per (batch, row). Ends with a plain
// per-block partial store — NO fence, NO atomic (round-14 post-mortem).
// All math paths byte-identical to rounds 10-14 (absmax=0 validated).
// ---------------------------------------------------------------------------
__global__ __launch_bounds__(256) void fused_edt_loss(
    const float* __restrict__ pred, const float* __restrict__ targ,
    const u64* __restrict__ colmask, const int* __restrict__ flags,
    double* __restrict__ partial) {
  const int b = blockIdx.x >> 8;       // batch 0..7
  const int i = blockIdx.x & (H - 1);  // row (block-uniform)
  const int j = threadIdx.x;           // column

  __shared__ __align__(16) float gPF[W], gPB[W], gTF[W], gTB[W];
  __shared__ double wsum[4];

  // ---- load this column's bits for both images (L2-resident, 64B) ----
  const ulonglong2* __restrict__ cp =
      (const ulonglong2*)(colmask + b * 1024 + j * 4);
  const ulonglong2* __restrict__ ct =
      (const ulonglong2*)(colmask + (8 + b) * 1024 + j * 4);
  const ulonglong2 p01 = cp[0], p23 = cp[1];
  const ulonglong2 t01 = ct[0], t23 = ct[1];
  const u64 p0 = p01.x, p1 = p01.y, p2 = p23.x, p3 = p23.y;
  const u64 t0 = t01.x, t1 = t01.y, t2 = t23.x, t3 = t23.y;
  const int pix = b * NPIX + i * W + j;
  const float p = pred[pix];
  const float t = targ[pix];

  // ---- uniform row-split masks (i block-uniform -> SGPR math) ----
  const int gi = i >> 6;
  const int bb = i & 63;
  const u64 lm = (~0ull) >> (63 - bb);  // bits 0..bb
  const u64 hm = (~0ull) << bb;         // bits bb..63
  const u64 k0 = gi == 0 ? lm : ~0ull;
  const u64 k1 = gi < 1 ? 0ull : (gi == 1 ? lm : ~0ull);
  const u64 k2 = gi < 2 ? 0ull : (gi == 2 ? lm : ~0ull);
  const u64 k3 = gi < 3 ? 0ull : lm;
  const u64 q0 = gi > 0 ? 0ull : hm;
  const u64 q1 = gi > 1 ? 0ull : (gi == 1 ? hm : ~0ull);
  const u64 q2 = gi > 2 ? 0ull : (gi == 2 ? hm : ~0ull);
  const u64 q3 = gi == 3 ? hm : ~0ull;

  // ---- vertical nearest-opposite distance, branch-free (validated) ----
#define VDIST(c0, c1, c2, c3, CL, DV2)                                \
  {                                                                   \
    const u64 cw = gi == 0 ? c0 : gi == 1 ? c1 : gi == 2 ? c2 : c3;   \
    CL = (int)((cw >> bb) & 1ull);                                    \
    const u64 inv = CL ? ~0ull : 0ull;                                \
    const u64 o0 = c0 ^ inv, o1 = c1 ^ inv, o2 = c2 ^ inv,            \
              o3 = c3 ^ inv;                                          \
    const u64 u0 = o0 & k0, u1 = o1 & k1, u2 = o2 & k2, u3 = o3 & k3; \
    int last = -30000;                                                \
    if (u0) last = 63 - __builtin_clzll(u0);                          \
    if (u1) last = 127 - __builtin_clzll(u1);                         \
    if (u2) last = 191 - __builtin_clzll(u2);                         \
    if (u3) last = 255 - __builtin_clzll(u3);                         \
    const u64 d0 = o0 & q0, d1 = o1 & q1, d2 = o2 & q2, d3 = o3 & q3; \
    int nxt = 30000;                                                  \
    if (d3) nxt = 192 + __builtin_ctzll(d3);                          \
    if (d2) nxt = 128 + __builtin_ctzll(d2);                          \
    if (d1) nxt = 64 + __builtin_ctzll(d1);                           \
    if (d0) nxt = __builtin_ctzll(d0);                                \
    const int up = i - last, dn = nxt - i;                            \
    const int dv = up < dn ? up : dn;                                 \
    DV2 = (dv >= 1000) ? BIG2 : (float)(dv * dv);                     \
  }
  int clP, clT;
  float dv2P, dv2T;
  VDIST(p0, p1, p2, p3, clP, dv2P)
  VDIST(t0, t1, t2, t3, clT, dv2T)
#undef VDIST

  // envelopes: g_fg[k] = (k fg) ? dv2 : 0 ; g_bg[k] = (k fg) ? 0 : dv2
  gPF[j] = clP ? dv2P : 0.0f;
  gPB[j] = clP ? 0.0f : dv2P;
  gTF[j] = clT ? dv2T : 0.0f;
  gTB[j] = clT ? 0.0f : dv2T;
  __syncthreads();

  // ---- pruned row scan (disjoint support: query own-class envelope) ----
  const float* __restrict__ baseP = clP ? gPF : gPB;
  const float* __restrict__ baseT = clT ? gTF : gTB;
  float bestP = dv2P, bestT = dv2T;  // k=j candidate
  for (int d = 1; d < W; ++d) {
    const float dd = (float)(d * d);
    if (__all((dd >= bestP) & (dd >= bestT))) break;
    const int kL = j - d, kR = j + d;
    const int kLc = kL < 0 ? 0 : kL;
    const int kRc = kR > W - 1 ? W - 1 : kR;
    const float cP = fminf(kL >= 0 ? baseP[kLc] : BIG2,
                           kR < W ? baseP[kRc] : BIG2);
    const float cT = fminf(kL >= 0 ? baseT[kLc] : BIG2,
                           kR < W ? baseT[kRc] : BIG2);
    bestP = fminf(bestP, cP + dd);
    bestT = fminf(bestT, cT + dd);
  }

  // ---- loss + block reduce; plain store (no fence, no atomic) ----
  const float fP = flags[b] ? 1.0f : 0.0f;  // zero field if no fg (ref)
  const float fT = flags[8 + b] ? 1.0f : 0.0f;
  const float pe = (p - t) * (p - t);
  double c = (double)(pe * (bestP * fP + bestT * fT));
  for (int off = 32; off > 0; off >>= 1) c += __shfl_down(c, off);
  if ((j & 63) == 0) wsum[j >> 6] = c;
  __syncthreads();
  if (j == 0) partial[blockIdx.x] = wsum[0] + wsum[1] + wsum[2] + wsum[3];
}

// ---------------------------------------------------------------------------
// Kernel D: reduce 2048 partials, scale, write fp32 result (round-10
// validated; summation order identical -> bit-identical output).
// ---------------------------------------------------------------------------
__global__ __launch_bounds__(256) void finalize(
    const double* __restrict__ partial, float* __restrict__ out) {
  double s = 0.0;
#pragma unroll
  for (int k = 0; k < 8; ++k) s += partial[threadIdx.x + (k << 8)];
  for (int off = 32; off > 0; off >>= 1) s += __shfl_down(s, off);
  __shared__ double ws[4];
  if ((threadIdx.x & 63) == 0) ws[threadIdx.x >> 6] = s;
  __syncthreads();
  if (threadIdx.x == 0)
    out[0] = (float)((ws[0] + ws[1] + ws[2] + ws[3]) *
                     (1.0 / (8.0 * (double)NPIX)));
}

extern "C" void kernel_launch(void* const* d_in, const int* in_sizes, int n_in,
                              void* d_out, int out_size, void* d_ws,
                              size_t ws_size, hipStream_t stream) {
  const float* pred = (const float*)d_in[0];
  const float* targ = (const float*)d_in[1];
  double* partial = (double*)d_ws;
  int* flags = (int*)((char*)d_ws + 16384);
  u64* rm2 = (u64*)((char*)d_ws + 32768);
  u64* colmask = (u64*)((char*)d_ws + 163840);

  hipMemsetAsync(flags, 0, 64, stream);  // zero fg.any() flags
  mask_build<<<256, 64, 0, stream>>>(pred, targ, rm2, flags);
  xpose_cols<<<64, 64, 0, stream>>>(rm2, colmask);
  fused_edt_loss<<<8 * H, 256, 0, stream>>>(pred, targ, colmask, flags,
                                            partial);
  finalize<<<1, 256, 0, stream>>>(partial, (float*)d_out);
}